// Round 8
// baseline (343.785 us; speedup 1.0000x reference)
//
#include <hip/hip_runtime.h>

// RankingLoss: B=16384 rows, D=1024 fp32, C=14 int32 labels -> scalar fp32.
//
// Round 8 = round 7's fusion with two bugs fixed:
//  (1) margins balloted at FULL wave-0 scope (round 7 balloted inside
//      threadIdx.x==0 -> only lane 0 active -> rows 1-3 margins lost);
//  (2) ticket at d_ws offset 0, partials at offset 16, with a runtime
//      ws_size guard (round 7 put the ticket at offset 16384 = possibly
//      one word past the workspace). Fallback: proven two-kernel path.
// Chassis = round-1 (best measured, 45.5 us): 4096 blocks, one 4-row group
// per block, 4 waves each own a D-quarter, single 10-load batch, ballot
// margins via LDS, XCD-bijective swizzle. Fused finish: store partial,
// threadfence, ticket atomicAdd; last block re-reduces all 4096 partials
// in the exact phase2 order (bitwise-identical output).

constexpr int D   = 1024;
constexpr int C   = 14;
constexpr int RPB = 4;   // output rows per block (one 4-row group)
constexpr int WPB = 4;   // waves per block; wave w covers D-quarter w

__device__ __forceinline__ float dot4(const float4 x, const float4 y) {
    return x.x * y.x + x.y * y.y + x.z * y.z + x.w * y.w;
}

template <bool FUSED>
__global__ __launch_bounds__(256) void rank_main(
    const float* __restrict__ zi, const float* __restrict__ zt,
    const int* __restrict__ labels, float* __restrict__ partial,
    unsigned int* __restrict__ ticket, float* __restrict__ out,
    int B, float invB)
{
    const int wave = threadIdx.x >> 6;
    const int lane = threadIdx.x & 63;

    // Bijective XCD swizzle (gridDim.x % 8 == 0).
    const int nwg = gridDim.x;
    const int wg  = (blockIdx.x & 7) * (nwg >> 3) + (blockIdx.x >> 3);

    const int r0  = wg * RPB;
    const int M   = B - 1;               // B is a power of two
    const int idx = (wave << 6) + lane;  // float4 index: wave w = quarter w

    __shared__ float red[WPB][12];
    __shared__ float mlds[RPB];
    __shared__ int   is_last;

    // Margins: FULL wave-0 scope ballots (all 64 lanes active); lanes 0..3
    // each finalize one row's margin into LDS.
    if (wave == 0) {
        const int kk = lane >> 4, c = lane & 15;
        int lx = 0, lo = 0;
        if (c < C) {
            const int ra = (r0 + kk)     & M;
            const int rb = (r0 + kk + 1) & M;
            const int li = labels[(size_t)ra * C + c];
            const int lj = labels[(size_t)rb * C + c];
            lx = li ^ lj;
            lo = li | lj;
        }
        const unsigned long long bx = __ballot(lx != 0);
        const unsigned long long bo = __ballot(lo != 0);
        if (lane < RPB) {
            const float dv = (float)__popcll((bx >> (16 * lane)) & 0x3FFFull);
            const float nv = (float)__popcll((bo >> (16 * lane)) & 0x3FFFull);
            mlds[lane] = (dv == 0.f) ? 0.f : fmaxf(0.5f, dv / nv);
        }
    }

    // Batch ALL 10 loads (5 rows x 2 tensors, one quarter each), then dots.
    float4 a[RPB + 1], b[RPB + 1];
    #pragma unroll
    for (int k = 0; k <= RPB; ++k) {
        const int r = (r0 + k) & M;
        a[k] = ((const float4*)(zi + (size_t)r * D))[idx];
        b[k] = ((const float4*)(zt + (size_t)r * D))[idx];
    }

    float v[12];
    #pragma unroll
    for (int k = 0; k < RPB; ++k) {
        v[k]     = dot4(a[k],     b[k]);      // paired   dot(zi[k],  zt[k])
        v[4 + k] = dot4(a[k + 1], b[k]);      // imp_img  dot(zi[k+1],zt[k])
        v[8 + k] = dot4(b[k + 1], a[k]);      // imp_txt  dot(zt[k+1],zi[k])
    }

    // Wave-reduce the 12 quarter-dot partials.
    #pragma unroll
    for (int off = 32; off > 0; off >>= 1) {
        #pragma unroll
        for (int i = 0; i < 12; ++i) v[i] += __shfl_down(v[i], off, 64);
    }
    if (lane == 0) {
        #pragma unroll
        for (int i = 0; i < 12; ++i) red[wave][i] = v[i];
    }
    __syncthreads();

    if (threadIdx.x == 0) {
        float local = 0.f;
        #pragma unroll
        for (int k = 0; k < RPB; ++k) {
            const float p  = red[0][k]     + red[1][k]     + red[2][k]     + red[3][k];
            const float di = red[0][4 + k] + red[1][4 + k] + red[2][4 + k] + red[3][4 + k];
            const float dt = red[0][8 + k] + red[1][8 + k] + red[2][8 + k] + red[3][8 + k];
            const float m  = mlds[k];
            local += fmaxf(di - p + m, 0.f) + fmaxf(dt - p + m, 0.f);
        }
        partial[wg] = local;
        if (FUSED) {
            __threadfence();                       // release partial store
            const unsigned t = atomicAdd(ticket, 1u);
            is_last = (t == (unsigned)(nwg - 1)) ? 1 : 0;
        }
    }

    if (FUSED) {
        __syncthreads();
        // Last-arriving block reduces all partials; algorithm/order is
        // bitwise identical to rank_phase2 -> output unchanged.
        if (is_last) {
            __threadfence();                       // acquire partial stores
            float s = 0.f;
            for (int i = threadIdx.x; i < nwg; i += 256) s += partial[i];
            #pragma unroll
            for (int off = 32; off > 0; off >>= 1) s += __shfl_down(s, off, 64);
            __shared__ float sm[4];
            if ((threadIdx.x & 63) == 0) sm[threadIdx.x >> 6] = s;
            __syncthreads();
            if (threadIdx.x == 0)
                out[0] = (sm[0] + sm[1] + sm[2] + sm[3]) * invB;
        }
    }
}

__global__ __launch_bounds__(256) void rank_phase2(
    const float* __restrict__ partial, float* __restrict__ out,
    int npart, float invB)
{
    float s = 0.f;
    for (int i = threadIdx.x; i < npart; i += 256) s += partial[i];
    #pragma unroll
    for (int off = 32; off > 0; off >>= 1) s += __shfl_down(s, off, 64);
    __shared__ float sm[4];
    if ((threadIdx.x & 63) == 0) sm[threadIdx.x >> 6] = s;
    __syncthreads();
    if (threadIdx.x == 0)
        out[0] = (sm[0] + sm[1] + sm[2] + sm[3]) * invB;
}

extern "C" void kernel_launch(void* const* d_in, const int* in_sizes, int n_in,
                              void* d_out, int out_size, void* d_ws, size_t ws_size,
                              hipStream_t stream) {
    const float* zi     = (const float*)d_in[0];
    const float* zt     = (const float*)d_in[1];
    const int*   labels = (const int*)d_in[2];
    float*       out    = (float*)d_out;

    const int B      = in_sizes[0] / D;  // 16384
    const int blocks = B / RPB;          // 4096
    const float invB = 1.0f / (float)B;

    // Fused layout: [u32 ticket, pad to 16] [blocks x f32 partials].
    const size_t need = 16 + (size_t)blocks * 4;
    if (ws_size >= need) {
        unsigned int* ticket  = (unsigned int*)d_ws;
        float*        partial = (float*)((char*)d_ws + 16);
        hipMemsetAsync(ticket, 0, 4, stream);
        rank_main<true><<<blocks, 256, 0, stream>>>(
            zi, zt, labels, partial, ticket, out, B, invB);
    } else {
        // Proven two-kernel fallback (fits in blocks*4 bytes).
        float* partial = (float*)d_ws;
        rank_main<false><<<blocks, 256, 0, stream>>>(
            zi, zt, labels, partial, nullptr, out, B, invB);
        rank_phase2<<<1, 256, 0, stream>>>(partial, out, blocks, invB);
    }
}

// Round 9
// 151.179 us; speedup vs baseline: 2.2740x; 2.2740x over previous
//
#include <hip/hip_runtime.h>

// RankingLoss: B=16384 rows, D=1024 fp32, C=14 int32 labels -> scalar fp32.
//
// Round 9: REVERT to the best harness-verified kernel (round 0, 149.6 us).
// Session conclusion: phase1 is memory-bound at the L2-miss read-service
// ceiling (~3 TB/s chip-wide; cf. m13 copy = 6.29 TB/s r+w => ~3.15 TB/s
// read). Evidence: five structural variants (naive / high-occupancy /
// low-traffic 16-row / global_load_lds counted-vmcnt pipeline / NT-
// partitioned) all pin at 46-51 us; dispatches with near-zero FETCH_SIZE
// (fully L3-resident) take the SAME time, ruling out HBM-side effects;
// VALU <=10%, occupancy-insensitive, zero LDS conflicts. The fused
// single-kernel finish (round 8) regressed 5x: 4096 same-address
// device-scope atomics serialize cross-XCD (~50ns each ~= +200 us).
// Two-kernel deterministic finish retained.

constexpr int D   = 1024;
constexpr int C   = 14;
constexpr int RPW = 4;          // output rows per wave
constexpr int WPB = 4;          // waves per block (256 threads)
constexpr int RPB = RPW * WPB;  // 16 output rows per block

__device__ __forceinline__ float dot4(const float4 x, const float4 y) {
    return x.x * y.x + x.y * y.y + x.z * y.z + x.w * y.w;
}

__global__ __launch_bounds__(256) void rank_phase1(
    const float* __restrict__ zi, const float* __restrict__ zt,
    const int* __restrict__ labels, float* __restrict__ partial, int B)
{
    const int wave = threadIdx.x >> 6;
    const int lane = threadIdx.x & 63;
    const int r0   = blockIdx.x * RPB + wave * RPW;
    const int M    = B - 1;  // B is a power of two

    // Wave-uniform row base pointers for rows r0..r0+4 (wrap at B).
    const float4* zi_r[RPW + 1];
    const float4* zt_r[RPW + 1];
    #pragma unroll
    for (int k = 0; k <= RPW; ++k) {
        const int r = (r0 + k) & M;
        zi_r[k] = (const float4*)(zi + (size_t)r * D);
        zt_r[k] = (const float4*)(zt + (size_t)r * D);
    }

    float p [RPW] = {0.f, 0.f, 0.f, 0.f};  // paired   dot(zi[k],  zt[k])
    float ii[RPW] = {0.f, 0.f, 0.f, 0.f};  // imp_img  dot(zi[k+1],zt[k])
    float it[RPW] = {0.f, 0.f, 0.f, 0.f};  // imp_txt  dot(zt[k+1],zi[k])

    #pragma unroll
    for (int j = 0; j < 4; ++j) {
        const int idx = lane + 64 * j;  // lanes contiguous -> 1 KiB/instr
        // Batch ALL 10 loads for this quarter before any FMA.
        float4 a[RPW + 1], b[RPW + 1];
        #pragma unroll
        for (int k = 0; k <= RPW; ++k) a[k] = zi_r[k][idx];
        #pragma unroll
        for (int k = 0; k <= RPW; ++k) b[k] = zt_r[k][idx];
        #pragma unroll
        for (int k = 0; k < RPW; ++k) {
            p [k] += dot4(a[k],     b[k]);
            ii[k] += dot4(a[k + 1], b[k]);
            it[k] += dot4(b[k + 1], a[k]);
        }
    }

    // Label margins via ballot: lane = 16*k + c covers class c of row r0+k.
    // Binary labels: dv = popcount(xor bits), nv = popcount(or bits).
    const int kk = lane >> 4;
    const int c  = lane & 15;
    int lx = 0, lo = 0;
    if (c < C) {
        const int ra = (r0 + kk)     & M;
        const int rb = (r0 + kk + 1) & M;
        const int li = labels[(size_t)ra * C + c];
        const int lj = labels[(size_t)rb * C + c];
        lx = li ^ lj;
        lo = li | lj;
    }
    const unsigned long long bx = __ballot(lx != 0);
    const unsigned long long bo = __ballot(lo != 0);

    // Wave-reduce the 12 dot partials (independent chains pipeline well).
    #pragma unroll
    for (int off = 32; off > 0; off >>= 1) {
        #pragma unroll
        for (int k = 0; k < RPW; ++k) {
            p [k] += __shfl_down(p [k], off, 64);
            ii[k] += __shfl_down(ii[k], off, 64);
            it[k] += __shfl_down(it[k], off, 64);
        }
    }

    float local = 0.f;
    if (lane == 0) {
        #pragma unroll
        for (int k = 0; k < RPW; ++k) {
            const float dv = (float)__popcll((bx >> (16 * k)) & 0x3FFFull);
            const float nv = (float)__popcll((bo >> (16 * k)) & 0x3FFFull);
            const float m  = (dv == 0.f) ? 0.f : fmaxf(0.5f, dv / nv);
            local += fmaxf(ii[k] - p[k] + m, 0.f)
                   + fmaxf(it[k] - p[k] + m, 0.f);
        }
    }

    __shared__ float smem[WPB];
    if (lane == 0) smem[wave] = local;
    __syncthreads();
    if (threadIdx.x == 0)
        partial[blockIdx.x] = smem[0] + smem[1] + smem[2] + smem[3];
}

__global__ __launch_bounds__(256) void rank_phase2(
    const float* __restrict__ partial, float* __restrict__ out,
    int npart, float invB)
{
    float s = 0.f;
    for (int i = threadIdx.x; i < npart; i += 256) s += partial[i];
    #pragma unroll
    for (int off = 32; off > 0; off >>= 1) s += __shfl_down(s, off, 64);
    __shared__ float sm[4];
    if ((threadIdx.x & 63) == 0) sm[threadIdx.x >> 6] = s;
    __syncthreads();
    if (threadIdx.x == 0)
        out[0] = (sm[0] + sm[1] + sm[2] + sm[3]) * invB;
}

extern "C" void kernel_launch(void* const* d_in, const int* in_sizes, int n_in,
                              void* d_out, int out_size, void* d_ws, size_t ws_size,
                              hipStream_t stream) {
    const float* zi     = (const float*)d_in[0];
    const float* zt     = (const float*)d_in[1];
    const int*   labels = (const int*)d_in[2];
    float*       out    = (float*)d_out;
    float*       ws     = (float*)d_ws;

    const int B      = in_sizes[0] / D;  // 16384
    const int blocks = B / RPB;          // 1024

    rank_phase1<<<blocks, 256, 0, stream>>>(zi, zt, labels, ws, B);
    rank_phase2<<<1, 256, 0, stream>>>(ws, out, blocks, 1.0f / (float)B);
}